// Round 2
// baseline (1525.404 us; speedup 1.0000x reference)
//
#include <hip/hip_runtime.h>

// Problem shape (fixed by the harness):
//   B=2, S=2048 -> T=4096 tokens, D=1024, F=4096, E=8 experts, top_k from device.
// All tensors are float32 (per reference). MFMA compute in bf16, fp32 accumulate.
#define T_TOK 4096
#define DIM   1024
#define FDIM  4096
#define NEXP  8

typedef __bf16 bf16x8 __attribute__((ext_vector_type(8)));
typedef float  f32x4  __attribute__((ext_vector_type(4)));

// ---------------------------------------------------------------------------
// Router: one wave per token. fp32 gate logits, softmax-free top-k (exp values;
// denominator cancels under renorm), append (token, weight) to expert buckets.
// ---------------------------------------------------------------------------
__global__ __launch_bounds__(64)
void moe_router(const float* __restrict__ x,
                const float* __restrict__ gw,
                const float* __restrict__ gb,
                const int*   __restrict__ topk_p,
                int*   __restrict__ counts,
                int*   __restrict__ bucket,
                float* __restrict__ bweight) {
    const int t = blockIdx.x;
    const int lane = threadIdx.x;
    float part[NEXP];
#pragma unroll
    for (int e = 0; e < NEXP; ++e) part[e] = 0.f;
    const float* xrow = x + (size_t)t * DIM;
    for (int i = lane; i < DIM; i += 64) {
        float xv = xrow[i];
#pragma unroll
        for (int e = 0; e < NEXP; ++e) part[e] += xv * gw[e * DIM + i];
    }
#pragma unroll
    for (int off = 32; off > 0; off >>= 1) {
#pragma unroll
        for (int e = 0; e < NEXP; ++e) part[e] += __shfl_xor(part[e], off);
    }
    if (lane == 0) {
        int k = topk_p[0];
        if (k < 1) k = 1;
        if (k > NEXP) k = NEXP;
        float logit[NEXP];
        float mx = -1e30f;
#pragma unroll
        for (int e = 0; e < NEXP; ++e) {
            logit[e] = part[e] + gb[e];
            mx = fmaxf(mx, logit[e]);
        }
        float p[NEXP];
#pragma unroll
        for (int e = 0; e < NEXP; ++e) p[e] = __expf(logit[e] - mx);
        bool used[NEXP];
#pragma unroll
        for (int e = 0; e < NEXP; ++e) used[e] = false;
        int   sel[NEXP];
        float selp[NEXP];
        float wsum = 0.f;
        for (int j = 0; j < k; ++j) {
            int best = 0; float bv = -1.f;
            for (int e = 0; e < NEXP; ++e) {
                if (!used[e] && p[e] > bv) { bv = p[e]; best = e; }  // ties -> lowest idx
            }
            used[best] = true;
            sel[j] = best;
            selp[j] = bv;
            wsum += bv;
        }
        for (int j = 0; j < k; ++j) {
            int e = sel[j];
            int pos = atomicAdd(&counts[e], 1);
            bucket[e * T_TOK + pos]  = t;
            bweight[e * T_TOK + pos] = selp[j] / wsum;
        }
    }
}

// fp32x8 -> bf16x8 helper (loads 2x float4, converts)
__device__ __forceinline__ bf16x8 ld_cvt8(const float* p) {
    float4 v0 = *(const float4*)p;
    float4 v1 = *(const float4*)(p + 4);
    bf16x8 t;
    t[0] = (__bf16)v0.x; t[1] = (__bf16)v0.y; t[2] = (__bf16)v0.z; t[3] = (__bf16)v0.w;
    t[4] = (__bf16)v1.x; t[5] = (__bf16)v1.y; t[6] = (__bf16)v1.z; t[7] = (__bf16)v1.w;
    return t;
}

// ---------------------------------------------------------------------------
// GEMM1: H[e, pos, fc] = silu( x[tok] . W1[e][:, f] + b1[e][f] ), H stored bf16.
// Block tile 64 (pairs) x 64 (f); 4 waves, wave w owns rows [16w, 16w+16).
// ---------------------------------------------------------------------------
__global__ __launch_bounds__(256)
void moe_gemm1(const float* __restrict__ x,
               const float* __restrict__ w1,
               const float* __restrict__ b1,
               const int*   __restrict__ counts,
               const int*   __restrict__ bucket,
               __bf16* __restrict__ H, int Fc, int chunk_f0) {
    const int e    = blockIdx.x >> 6;   // T_TOK/64 = 64 row-tiles per expert
    const int tile = blockIdx.x & 63;
    const int cnt  = counts[e];
    if (tile * 64 >= cnt) return;
    const int by = blockIdx.y;

    __shared__ __bf16 As[64][32];
    __shared__ __bf16 Bs[32][64];
    __shared__ int tok_s[64];

    const int tid = threadIdx.x;
    if (tid < 64) {
        int r = tile * 64 + tid;
        if (r >= cnt) r = cnt - 1;            // clamp padded rows (results unused)
        tok_s[tid] = bucket[e * T_TOK + r];
    }
    __syncthreads();

    const int wave = tid >> 6, lane = tid & 63;
    const int quad = lane >> 4, l15 = lane & 15;
    f32x4 acc[4];
#pragma unroll
    for (int n = 0; n < 4; ++n) acc[n] = (f32x4){0.f, 0.f, 0.f, 0.f};

    const float* w1e = w1 + (size_t)e * DIM * FDIM;
    const int arow = tid >> 2, acol = (tid & 3) * 8;   // A: 64 rows x 32 k
    const int brow = tid >> 3, bcol = (tid & 7) * 8;   // B: 32 k x 64 cols

    for (int k0 = 0; k0 < DIM; k0 += 32) {
        *(bf16x8*)&As[arow][acol] =
            ld_cvt8(&x[(size_t)tok_s[arow] * DIM + k0 + acol]);
        *(bf16x8*)&Bs[brow][bcol] =
            ld_cvt8(&w1e[(size_t)(k0 + brow) * FDIM + chunk_f0 + by * 64 + bcol]);
        __syncthreads();
        bf16x8 a = *(const bf16x8*)&As[wave * 16 + l15][quad * 8];
#pragma unroll
        for (int n = 0; n < 4; ++n) {
            bf16x8 b;
#pragma unroll
            for (int j = 0; j < 8; ++j) b[j] = Bs[quad * 8 + j][n * 16 + l15];
            acc[n] = __builtin_amdgcn_mfma_f32_16x16x32_bf16(a, b, acc[n], 0, 0, 0);
        }
        __syncthreads();
    }

#pragma unroll
    for (int n = 0; n < 4; ++n) {
#pragma unroll
        for (int r = 0; r < 4; ++r) {
            int m = wave * 16 + quad * 4 + r;        // C/D: row = quad*4+reg
            int prow = tile * 64 + m;
            if (prow < cnt) {
                int fc = by * 64 + n * 16 + l15;     // C/D: col = lane&15
                float v = acc[n][r] + b1[e * FDIM + chunk_f0 + fc];
                float s = v / (1.f + __expf(-v));    // silu
                H[(size_t)(e * T_TOK + prow) * Fc + fc] = (__bf16)s;
            }
        }
    }
}

// ---------------------------------------------------------------------------
// GEMM2: out[tok, d] += weight * ( H[e,pos,:] . W2[e][:, d] + b2[e][d] )
// K runs over the F-chunk; fp32 atomics straight into d_out.
// ---------------------------------------------------------------------------
__global__ __launch_bounds__(256)
void moe_gemm2(const __bf16* __restrict__ H,
               const float* __restrict__ w2,
               const float* __restrict__ b2,
               const int*   __restrict__ counts,
               const int*   __restrict__ bucket,
               const float* __restrict__ bweight,
               float* __restrict__ out, int Fc, int chunk_f0, int add_bias) {
    const int e    = blockIdx.x >> 6;
    const int tile = blockIdx.x & 63;
    const int cnt  = counts[e];
    if (tile * 64 >= cnt) return;
    const int by = blockIdx.y;   // D tiles: DIM/64 = 16

    __shared__ __bf16 As[64][32];
    __shared__ __bf16 Bs[32][64];
    __shared__ int   tok_s[64];
    __shared__ float w_s[64];

    const int tid = threadIdx.x;
    if (tid < 64) {
        int r  = tile * 64 + tid;
        int rc = r < cnt ? r : cnt - 1;
        tok_s[tid] = bucket[e * T_TOK + rc];
        w_s[tid]   = bweight[e * T_TOK + rc];
    }
    __syncthreads();

    const int wave = tid >> 6, lane = tid & 63;
    const int quad = lane >> 4, l15 = lane & 15;
    f32x4 acc[4];
#pragma unroll
    for (int n = 0; n < 4; ++n) acc[n] = (f32x4){0.f, 0.f, 0.f, 0.f};

    const float* w2e = w2 + (size_t)e * FDIM * DIM;
    const int arow = tid >> 2, acol = (tid & 3) * 8;
    const int brow = tid >> 3, bcol = (tid & 7) * 8;

    for (int k0 = 0; k0 < Fc; k0 += 32) {
        *(bf16x8*)&As[arow][acol] =                  // H is already bf16
            *(const bf16x8*)&H[(size_t)(e * T_TOK + tile * 64 + arow) * Fc + k0 + acol];
        *(bf16x8*)&Bs[brow][bcol] =
            ld_cvt8(&w2e[(size_t)(chunk_f0 + k0 + brow) * DIM + by * 64 + bcol]);
        __syncthreads();
        bf16x8 a = *(const bf16x8*)&As[wave * 16 + l15][quad * 8];
#pragma unroll
        for (int n = 0; n < 4; ++n) {
            bf16x8 b;
#pragma unroll
            for (int j = 0; j < 8; ++j) b[j] = Bs[quad * 8 + j][n * 16 + l15];
            acc[n] = __builtin_amdgcn_mfma_f32_16x16x32_bf16(a, b, acc[n], 0, 0, 0);
        }
        __syncthreads();
    }

#pragma unroll
    for (int n = 0; n < 4; ++n) {
#pragma unroll
        for (int r = 0; r < 4; ++r) {
            int m = wave * 16 + quad * 4 + r;
            int prow = tile * 64 + m;
            if (prow < cnt) {
                int dc = by * 64 + n * 16 + l15;
                float v = acc[n][r];
                if (add_bias) v += b2[e * DIM + dc];
                atomicAdd(&out[(size_t)tok_s[m] * DIM + dc], w_s[m] * v);
            }
        }
    }
}

extern "C" void kernel_launch(void* const* d_in, const int* in_sizes, int n_in,
                              void* d_out, int out_size, void* d_ws, size_t ws_size,
                              hipStream_t stream) {
    const float* x  = (const float*)d_in[0];
    const float* gw = (const float*)d_in[1];
    const float* gb = (const float*)d_in[2];
    const float* w1 = (const float*)d_in[3];
    const float* b1 = (const float*)d_in[4];
    const float* w2 = (const float*)d_in[5];
    const float* b2 = (const float*)d_in[6];
    const int* topk  = (const int*)d_in[7];
    float* out = (float*)d_out;

    // Workspace layout (re-poisoned 0xAA before every launch; init what we use)
    char* ws = (char*)d_ws;
    size_t off = 0;
    int* counts = (int*)(ws + off);   off += 256;
    int* bucket = (int*)(ws + off);   off += (size_t)NEXP * T_TOK * 4;  // 128 KB
    float* bw   = (float*)(ws + off); off += (size_t)NEXP * T_TOK * 4;  // 128 KB
    off = (off + 255) & ~(size_t)255;
    __bf16* H = (__bf16*)(ws + off);
    size_t rem = ws_size > off ? ws_size - off : 0;

    // Largest F-chunk whose H buffer (worst-case k=E routing) fits in ws.
    int Fc = 64;
    const int cands[7] = {4096, 2048, 1024, 512, 256, 128, 64};
    for (int ci = 0; ci < 7; ++ci) {
        if ((size_t)NEXP * T_TOK * cands[ci] * 2 <= rem) { Fc = cands[ci]; break; }
    }

    hipMemsetAsync(out, 0, (size_t)out_size * 4, stream);
    hipMemsetAsync(counts, 0, 256, stream);

    moe_router<<<T_TOK, 64, 0, stream>>>(x, gw, gb, topk, counts, bucket, bw);

    const int nchunk = FDIM / Fc;
    for (int c = 0; c < nchunk; ++c) {
        int f0 = c * Fc;
        dim3 g1(NEXP * (T_TOK / 64), Fc / 64);
        moe_gemm1<<<g1, 256, 0, stream>>>(x, w1, b1, counts, bucket, H, Fc, f0);
        dim3 g2(NEXP * (T_TOK / 64), DIM / 64);
        moe_gemm2<<<g2, 256, 0, stream>>>(H, w2, b2, counts, bucket, bw, out,
                                          Fc, f0, c == 0 ? 1 : 0);
    }
}